// Round 9
// baseline (120.526 us; speedup 1.0000x reference)
//
#include <hip/hip_runtime.h>
#include <hip/hip_bf16.h>

// Problem constants: B=2, T=2048, D=1024, H=16, DK=64
// Math reduction: y = permute(x @ Wv) @ Wo^T  (softmax rowsum == 1 exactly;
// reference's einsum 'bhtl,bthd->bhtd' never contracts v with A over l, so
// o[b,h,t,:] = (sum_l A[b,h,t,l]) * v[b,t,h,:] = v[b,t,h,:]).
// Permute: V[b*2048+t][h*64+k] -> Vp[b*2048 + h*128 + t/16][(t%16)*64 + k]
// Inputs/outputs FP32 (reference dtype); internal bf16 MFMA, fp32 accum.
// R8 postmortem: latency fixes (dbuf, vmcnt(N), occupancy) all neutral ->
// GEMM is LDS-throughput-bound (~72 KB/CU/iter). R9: 32x32x16 MFMA with
// 64x64 wave tiles reads 2 B LDS per output per K32 (vs 3 B for 16x16x32)
// and runs 13% faster per FLOP. 128-thr blocks (2 waves), tile 128x64,
// 4 blocks/CU; R8's 3-buffer raw-barrier pipeline kept (6 DMA/batch ->
// vmcnt(6)). Block-id swizzle: 16 consecutive ids share one A-panel.

using bf16 = __hip_bfloat16;
typedef __attribute__((ext_vector_type(8))) short bf16x8;    // 8 bf16 = 4 VGPRs
typedef __attribute__((ext_vector_type(16))) float f32x16;   // 32x32 acc

__device__ __forceinline__ void gld_lds16(const void* g, void* l) {
    // async global->LDS, 16B/lane; LDS dest = wave-uniform base + lane*16
    __builtin_amdgcn_global_load_lds(
        (const __attribute__((address_space(1))) void*)g,
        (__attribute__((address_space(3))) void*)l, 16, 0, 0);
}

// ---- fused prep: Wv transpose+cvt | x cvt | Wo cvt, one dispatch ----------
__global__ __launch_bounds__(256) void prep(const float* __restrict__ x,
                                            const float* __restrict__ Wv,
                                            const float* __restrict__ Wo,
                                            bf16* __restrict__ xb,
                                            bf16* __restrict__ WvT,
                                            bf16* __restrict__ Wob) {
    __shared__ float tile[64][65];
    const int id = blockIdx.x;
    const int t  = threadIdx.x;
    if (id < 256) {                       // Wv transpose+convert (64x64 tile)
        const int bx = id & 15, by = id >> 4;
        const int c = t & 63, r4 = t >> 6;
#pragma unroll
        for (int p = 0; p < 16; ++p) {
            int r = p * 4 + r4;
            tile[r][c] = Wv[(size_t)(by * 64 + r) * 1024 + bx * 64 + c];
        }
        __syncthreads();
#pragma unroll
        for (int p = 0; p < 16; ++p) {
            int r = p * 4 + r4;
            WvT[(size_t)(bx * 64 + r) * 1024 + by * 64 + c] = __float2bfloat16(tile[c][r]);
        }
    } else if (id < 4352) {               // x -> bf16, float4 per thread
        const int i = (id - 256) * 256 + t;
        const float4 v = ((const float4*)x)[i];
        bf16 o[4] = {__float2bfloat16(v.x), __float2bfloat16(v.y),
                     __float2bfloat16(v.z), __float2bfloat16(v.w)};
        ((ulong1*)xb)[i] = *(ulong1*)o;
    } else {                              // Wo -> bf16
        const int i = (id - 4352) * 256 + t;
        const float4 v = ((const float4*)Wo)[i];
        bf16 o[4] = {__float2bfloat16(v.x), __float2bfloat16(v.y),
                     __float2bfloat16(v.z), __float2bfloat16(v.w)};
        ((ulong1*)Wob)[i] = *(ulong1*)o;
    }
}

// ---------------- GEMM  C = A(Mx1024) * Bt(Nx1024)^T -----------------------
// 128x64 tile / 128 threads (2 waves stacked in M, each 64x64 via 2x2 of
// 32x32x16 MFMA). LDS buffer: A 128x32 @ [0:4096], B 64x32 @ [4096:6144].
// 16B-chunk XOR swizzle: slot s of row r holds global chunk s ^ ((r>>1)&3).
__device__ __forceinline__ void storeC(float v, bf16* p)  { *p = __float2bfloat16(v); }
__device__ __forceinline__ void storeC(float v, float* p) { *p = v; }

template <bool PERMUTE, typename OutT>
__global__ __launch_bounds__(128, 2) void gemm_bt(const bf16* __restrict__ A,
                                                  const bf16* __restrict__ Bt,
                                                  OutT* __restrict__ C) {
    __shared__ __align__(16) bf16 st[3][6144];    // 3 x 12 KB = 36 KB

    const int tid  = threadIdx.x;
    const int wave = tid >> 6;            // 0,1
    const int lane = tid & 63;
    const int id = blockIdx.x;            // swizzle: 16 consecutive ids share A-panel
    const int m0 = (id >> 4) * 128;
    const int n0 = (id & 15) * 64;
    const int wr = wave * 64;             // wave's 64-row half (M)

    // staging: per-wave 6 DMAs/batch (A d=0..3 rows wave*64+d*16; B d=0..1
    // rows wave*32+d*16). Lane covers (row = lane>>2, chunk slot = lane&3);
    // slot s holds global chunk s ^ ((row>>1)&3)  [(lane>>3)&3 == (row>>1)&3].
    const int srow = lane >> 2;
    const int scol = (((lane & 3) ^ ((lane >> 3) & 3)) & 3) * 8;
    const bf16* gA = A  + (size_t)(m0 + wave * 64 + srow) * 1024 + scol;
    const bf16* gB = Bt + (size_t)(n0 + wave * 32 + srow) * 1024 + scol;

    auto stage = [&](bf16* s, int kt) {
#pragma unroll
        for (int d = 0; d < 4; ++d)       // A: 4 x 16 rows
            gld_lds16(gA + kt + d * 16384, s + wave * 2048 + d * 512);
#pragma unroll
        for (int d = 0; d < 2; ++d)       // B: 2 x 16 rows
            gld_lds16(gB + kt + d * 16384, s + 4096 + wave * 1024 + d * 512);
    };

    f32x16 acc[2][2];
#pragma unroll
    for (int i = 0; i < 2; ++i)
#pragma unroll
        for (int j = 0; j < 2; ++j)
#pragma unroll
            for (int r = 0; r < 16; ++r)
                acc[i][j][r] = 0.f;

    const int l31 = lane & 31;            // row (A) / col (B) within 32-block
    const int h   = lane >> 5;            // k-half selector
    const int xsw = (lane >> 1) & 3;      // == ((l31)>>1)&3, row-XOR bits

    // prologue: batches 0,1 -> bufs 0,1 (12 DMAs outstanding per wave)
    stage(st[0], 0);
    stage(st[1], 32);

#pragma unroll 1
    for (int i = 0; i < 32; ++i) {
        if (i < 31)
            asm volatile("s_waitcnt vmcnt(6)" ::: "memory");   // oldest batch done
        else
            asm volatile("s_waitcnt vmcnt(0)" ::: "memory");   // final batch done
        asm volatile("s_barrier" ::: "memory");                // raw: no vmcnt(0) drain
        if (i < 30)                       // batch i+2 post-barrier (WAR-safe)
            stage(st[(i + 2) % 3], (i + 2) * 32);

        const bf16* sb = st[i % 3];
#pragma unroll
        for (int s = 0; s < 2; ++s) {     // two K=16 MFMA steps per BK=32
            const int slot = ((2 * s + h) ^ xsw) * 8;
            bf16x8 aF[2], bF[2];
#pragma unroll
            for (int ii = 0; ii < 2; ++ii)
                aF[ii] = *(const bf16x8*)&sb[(wr + ii * 32 + l31) * 32 + slot];
#pragma unroll
            for (int j = 0; j < 2; ++j)
                bF[j] = *(const bf16x8*)&sb[4096 + (j * 32 + l31) * 32 + slot];
#pragma unroll
            for (int ii = 0; ii < 2; ++ii)
#pragma unroll
                for (int j = 0; j < 2; ++j)
                    acc[ii][j] = __builtin_amdgcn_mfma_f32_32x32x16_bf16(
                        aF[ii], bF[j], acc[ii][j], 0, 0, 0);
        }
    }

    // epilogue: 32x32 C/D layout col=lane&31, row=(reg&3)+8*(reg>>2)+4*(lane>>5)
    const int rbase = 4 * h;
#pragma unroll
    for (int ii = 0; ii < 2; ++ii) {
#pragma unroll
        for (int j = 0; j < 2; ++j) {
            const int col = n0 + j * 32 + l31;
#pragma unroll
            for (int r = 0; r < 16; ++r) {
                const int row = m0 + wr + ii * 32 + (r & 3) + 8 * (r >> 2) + rbase;
                if (PERMUTE) {
                    const int b = row >> 11, t = row & 2047;
                    const int hh = col >> 6, k = col & 63;
                    const int rr = (b << 11) | (hh << 7) | (t >> 4);
                    const int cc = ((t & 15) << 6) | k;
                    storeC(acc[ii][j][r], &C[(size_t)rr * 1024 + cc]);
                } else {
                    storeC(acc[ii][j][r], &C[(size_t)row * 1024 + col]);
                }
            }
        }
    }
}

extern "C" void kernel_launch(void* const* d_in, const int* in_sizes, int n_in,
                              void* d_out, int out_size, void* d_ws, size_t ws_size,
                              hipStream_t stream) {
    (void)in_sizes; (void)n_in; (void)out_size; (void)ws_size;
    // inputs (fp32): x, mask, Wq, Wk, Wv, Wo  (mask/Wq/Wk dead — see header)
    const float* x  = (const float*)d_in[0];
    const float* Wv = (const float*)d_in[4];
    const float* Wo = (const float*)d_in[5];
    float* out = (float*)d_out;

    bf16* xb    = (bf16*)d_ws;                 // 4096*1024 bf16 = 8 MB
    bf16* WvT   = xb    + 4096 * 1024;         // 2 MB
    bf16* Wob   = WvT   + 1024 * 1024;         // 2 MB
    bf16* vperm = Wob   + 1024 * 1024;         // 8 MB   (total 20 MB)

    prep<<<5376, 256, 0, stream>>>(x, Wv, Wo, xb, WvT, Wob);
    // V = x @ Wv, written permuted (bf16)
    gemm_bt<true,  bf16 ><<<512, 128, 0, stream>>>(xb, WvT, vperm);
    // y = Vp @ Wo^T  (fp32 output)
    gemm_bt<false, float><<<512, 128, 0, stream>>>(vperm, Wob, out);
}

// Round 10
// 115.075 us; speedup vs baseline: 1.0474x; 1.0474x over previous
//
#include <hip/hip_runtime.h>
#include <hip/hip_bf16.h>

// Problem constants: B=2, T=2048, D=1024, H=16, DK=64
// Math reduction: y = permute(x @ Wv) @ Wo^T  (softmax rowsum == 1 exactly;
// reference's einsum 'bhtl,bthd->bhtd' never contracts v with A over l, so
// o[b,h,t,:] = (sum_l A[b,h,t,l]) * v[b,t,h,:] = v[b,t,h,:]).
// Permute: V[b*2048+t][h*64+k] -> Vp[b*2048 + h*128 + t/16][(t%16)*64 + k]
// Inputs/outputs FP32 (reference dtype); internal bf16 MFMA, fp32 accum.
// R10 = REVERT to R8 (best measured: 115.3 us). R9's 32x32 restructure
// regressed (+5.2 us: halved waves/CU outweighed the LDS-bytes saving).
// Session ledger: fixed harness overhead 64 us (R7 wall-vs-kernel), kernel
// sum ~51 us; occupancy/dbuf/swizzle/vmcnt-pipeline/MFMA-shape each moved
// <= 2.6 us; persistent fusion +152 us (grid barriers ~100 us each on
// non-coherent XCDs); fp8 internals excluded by error arithmetic.

using bf16 = __hip_bfloat16;
typedef __attribute__((ext_vector_type(8))) short bf16x8;   // 8 bf16 = 4 VGPRs
typedef __attribute__((ext_vector_type(4))) float f32x4;

__device__ __forceinline__ void gld_lds16(const void* g, void* l) {
    // async global->LDS, 16B/lane; LDS dest = wave-uniform base + lane*16
    __builtin_amdgcn_global_load_lds(
        (const __attribute__((address_space(1))) void*)g,
        (__attribute__((address_space(3))) void*)l, 16, 0, 0);
}

// ---- fused prep: Wv transpose+cvt | x cvt | Wo cvt, one dispatch ----------
__global__ __launch_bounds__(256) void prep(const float* __restrict__ x,
                                            const float* __restrict__ Wv,
                                            const float* __restrict__ Wo,
                                            bf16* __restrict__ xb,
                                            bf16* __restrict__ WvT,
                                            bf16* __restrict__ Wob) {
    __shared__ float tile[64][65];
    const int id = blockIdx.x;
    const int t  = threadIdx.x;
    if (id < 256) {                       // Wv transpose+convert (64x64 tile)
        const int bx = id & 15, by = id >> 4;
        const int c = t & 63, r4 = t >> 6;
#pragma unroll
        for (int p = 0; p < 16; ++p) {
            int r = p * 4 + r4;
            tile[r][c] = Wv[(size_t)(by * 64 + r) * 1024 + bx * 64 + c];
        }
        __syncthreads();
#pragma unroll
        for (int p = 0; p < 16; ++p) {
            int r = p * 4 + r4;
            WvT[(size_t)(bx * 64 + r) * 1024 + by * 64 + c] = __float2bfloat16(tile[c][r]);
        }
    } else if (id < 4352) {               // x -> bf16, float4 per thread
        const int i = (id - 256) * 256 + t;
        const float4 v = ((const float4*)x)[i];
        bf16 o[4] = {__float2bfloat16(v.x), __float2bfloat16(v.y),
                     __float2bfloat16(v.z), __float2bfloat16(v.w)};
        ((ulong1*)xb)[i] = *(ulong1*)o;
    } else {                              // Wo -> bf16
        const int i = (id - 4352) * 256 + t;
        const float4 v = ((const float4*)Wo)[i];
        bf16 o[4] = {__float2bfloat16(v.x), __float2bfloat16(v.y),
                     __float2bfloat16(v.z), __float2bfloat16(v.w)};
        ((ulong1*)Wob)[i] = *(ulong1*)o;
    }
}

// ---------------- GEMM  C = A(Mx1024) * Bt(Nx1024)^T -----------------------
// A, Bt bf16 row-major [.][K]: both operands K-contiguous.
// 128x64 tile / 256 threads; 4 waves 2x2, each 64x32 = 4x2 accs.
// Triple-buffered LDS, 2 DMA batches in flight, raw s_barrier + vmcnt(3).
__device__ __forceinline__ void storeC(float v, bf16* p)  { *p = __float2bfloat16(v); }
__device__ __forceinline__ void storeC(float v, float* p) { *p = v; }

template <bool PERMUTE, typename OutT>
__global__ __launch_bounds__(256) void gemm_bt(const bf16* __restrict__ A,
                                               const bf16* __restrict__ Bt,
                                               OutT* __restrict__ C) {
    __shared__ __align__(16) bf16 st[3][6144];    // 3 x 12 KB = 36 KB

    const int tid  = threadIdx.x;
    const int wave = tid >> 6;
    const int lane = tid & 63;
    const int m0 = blockIdx.x * 128;
    const int n0 = blockIdx.y * 64;

    const int wr = (wave >> 1) * 64;      // wave quadrant of 128x64 tile
    const int wc = (wave & 1) * 32;

    // staging: thread t covers tile row tid>>2, 16B chunk slot tid&3.
    // Swizzle: slot s of row r holds global chunk g = s ^ ((r>>1)&3).
    const int srow = tid >> 2;
    const int scol = (((tid & 3) ^ ((tid >> 3) & 3)) & 3) * 8;
    const bf16* gA = A  + (size_t)(m0 + srow) * 1024 + scol;
    const bf16* gB = Bt + (size_t)(n0 + srow) * 1024 + scol;
    const int woff = wave * 512;          // elems, wave-uniform LDS base

    f32x4 acc[4][2];
#pragma unroll
    for (int i = 0; i < 4; ++i)
#pragma unroll
        for (int j = 0; j < 2; ++j)
            acc[i][j] = (f32x4){0.f, 0.f, 0.f, 0.f};

    const int fr = lane & 15;
    const int q8 = ((((lane >> 4) ^ (lane >> 1)) & 3)) * 8;  // swizzled slot

    // prologue: batches 0,1 -> bufs 0,1 (6 DMAs outstanding per wave)
#pragma unroll
    for (int b = 0; b < 2; ++b) {
        bf16* s = st[b];
        const int kt = b * 32;
        gld_lds16(gA + kt,             s + woff);
        gld_lds16(gA + kt + 64 * 1024, s + 2048 + woff);
        gld_lds16(gB + kt,             s + 4096 + woff);
    }

#pragma unroll 1
    for (int i = 0; i < 32; ++i) {
        if (i < 31)
            asm volatile("s_waitcnt vmcnt(3)" ::: "memory");   // oldest batch done
        else
            asm volatile("s_waitcnt vmcnt(0)" ::: "memory");   // final batch done
        asm volatile("s_barrier" ::: "memory");                // raw: no vmcnt(0) drain
        if (i < 30) {                     // batch i+2 -> buf (i+2)%3 (post-barrier: WAR-safe)
            const int kt = (i + 2) * 32;
            bf16* s = st[(i + 2) % 3];
            gld_lds16(gA + kt,             s + woff);
            gld_lds16(gA + kt + 64 * 1024, s + 2048 + woff);
            gld_lds16(gB + kt,             s + 4096 + woff);
        }

        const bf16* sAb = st[i % 3];
        const bf16* sBb = st[i % 3] + 4096;
        bf16x8 aF[4], bF[2];
#pragma unroll
        for (int ii = 0; ii < 4; ++ii)
            aF[ii] = *(const bf16x8*)&sAb[(wr + ii * 16 + fr) * 32 + q8];
#pragma unroll
        for (int j = 0; j < 2; ++j)
            bF[j] = *(const bf16x8*)&sBb[(wc + j * 16 + fr) * 32 + q8];
#pragma unroll
        for (int ii = 0; ii < 4; ++ii)
#pragma unroll
            for (int j = 0; j < 2; ++j)
                acc[ii][j] = __builtin_amdgcn_mfma_f32_16x16x32_bf16(
                    aF[ii], bF[j], acc[ii][j], 0, 0, 0);
    }

    // epilogue: C/D layout col=lane&15, row=(lane>>4)*4+reg  [m91-verified]
#pragma unroll
    for (int i = 0; i < 4; ++i) {
#pragma unroll
        for (int j = 0; j < 2; ++j) {
            const int col = n0 + wc + j * 16 + (lane & 15);
#pragma unroll
            for (int r = 0; r < 4; ++r) {
                const int row = m0 + wr + i * 16 + (lane >> 4) * 4 + r;
                if (PERMUTE) {
                    const int b = row >> 11, t = row & 2047;
                    const int h = col >> 6,  k = col & 63;
                    const int rr = (b << 11) | (h << 7) | (t >> 4);
                    const int cc = ((t & 15) << 6) | k;
                    storeC(acc[i][j][r], &C[(size_t)rr * 1024 + cc]);
                } else {
                    storeC(acc[i][j][r], &C[(size_t)row * 1024 + col]);
                }
            }
        }
    }
}

extern "C" void kernel_launch(void* const* d_in, const int* in_sizes, int n_in,
                              void* d_out, int out_size, void* d_ws, size_t ws_size,
                              hipStream_t stream) {
    (void)in_sizes; (void)n_in; (void)out_size; (void)ws_size;
    // inputs (fp32): x, mask, Wq, Wk, Wv, Wo  (mask/Wq/Wk dead — see header)
    const float* x  = (const float*)d_in[0];
    const float* Wv = (const float*)d_in[4];
    const float* Wo = (const float*)d_in[5];
    float* out = (float*)d_out;

    bf16* xb    = (bf16*)d_ws;                 // 4096*1024 bf16 = 8 MB
    bf16* WvT   = xb    + 4096 * 1024;         // 2 MB
    bf16* Wob   = WvT   + 1024 * 1024;         // 2 MB
    bf16* vperm = Wob   + 1024 * 1024;         // 8 MB   (total 20 MB)

    prep<<<5376, 256, 0, stream>>>(x, Wv, Wo, xb, WvT, Wob);
    // V = x @ Wv, written permuted (bf16)
    gemm_bt<true,  bf16 ><<<dim3(32, 16), 256, 0, stream>>>(xb, WvT, vperm);
    // y = Vp @ Wo^T  (fp32 output)
    gemm_bt<false, float><<<dim3(32, 16), 256, 0, stream>>>(vperm, Wob, out);
}